// Round 12
// baseline (5357.635 us; speedup 1.0000x reference)
//
#include <hip/hip_runtime.h>
#include <math.h>

#define E32   32
#define Hh    4
#define Lh    3
#define SP    15
#define SM    74
#define EPSF  1e-5f

// wave-synchronous fence: per-wave DS ops execute in order; this stops the
// compiler from reordering LDS accesses across phase boundaries.
#define WSYNC() do { __builtin_amdgcn_wave_barrier(); asm volatile("" ::: "memory"); } while (0)

#define XS_STRIDE 36
#define OO_STRIDE 36
#define SC_FLOATS 960          // FFN half-buffer [15 x 64]; also holds oo [15 x 36]
#define SAMP_LDS  1504         // 544 (xs) + 960 (scratch)

// ---------------------------------------------------------------------------
// Setup: fuse pre_qkv into attention in-projections; K-mats pre-scaled by
// 1/sqrt(8); block 18 builds the positional-encoding table.
// ---------------------------------------------------------------------------
__global__ void fuse_weights(const float* pre_w, const float* pre_b,
                             const float* sa_inw, const float* sa_inb,
                             const float* cpre_w, const float* cpre_b,
                             const float* ca_inw, const float* ca_inb,
                             float* fw, float* fb, float* pe) {
    int id = blockIdx.x;            // 0..17 weights, 18 = PE table
    if (id == 18) {
        for (int i = threadIdx.x; i < SP * 32; i += blockDim.x) {
            int s = i >> 5, e = i & 31;
            float div = expf(-(float)(e & ~1) * 0.28782313662425572f); // ln(1e4)/32
            float ang = (float)s * div;
            pe[i] = (e & 1) ? cosf(ang) : sinf(ang);
        }
        return;
    }
    int l = id / 6, which = id % 6;
    int j = which % 3;
    bool cross = which >= 3;
    float scale = (j == 1) ? 0.35355339059327373f : 1.f;   // fold 1/sqrt(Dh) into K
    const float* A  = (cross ? ca_inw : sa_inw) + l * 96 * 32 + j * 32 * 32;
    const float* ab = (cross ? ca_inb : sa_inb) + l * 96 + j * 32;
    const float* P  = (cross ? cpre_w : pre_w) + (l * 3 + j) * 1024;
    const float* pb = (cross ? cpre_b : pre_b) + (l * 3 + j) * 32;
    float* W = fw + id * 1024;
    float* b = fb + id * 32;
    for (int i = threadIdx.x; i < 1024; i += blockDim.x) {
        int e = i >> 5, k = i & 31;
        float acc = 0.f;
        #pragma unroll
        for (int m = 0; m < 32; ++m) acc += A[e * 32 + m] * P[m * 32 + k];
        W[i] = acc * scale;
    }
    for (int e = threadIdx.x; e < 32; e += blockDim.x) {
        float acc = ab[e];
        #pragma unroll
        for (int m = 0; m < 32; ++m) acc += A[e * 32 + m] * pb[m];
        b[e] = acc * scale;
    }
}

// ---------------------------------------------------------------------------
// Wave-local building blocks (one 64-lane wave owns one sample; no
// __syncthreads anywhere in pan_main).
// ---------------------------------------------------------------------------

// 32-wide dot with 4 partial accumulators (ILP)
__device__ inline float dot32(const float* a, const float* b) {
    float p0 = 0.f, p1 = 0.f, p2 = 0.f, p3 = 0.f;
    #pragma unroll
    for (int k = 0; k < 32; k += 4) {
        p0 += a[k] * b[k];
        p1 += a[k + 1] * b[k + 1];
        p2 += a[k + 2] * b[k + 2];
        p3 += a[k + 3] * b[k + 3];
    }
    return (p0 + p1) + (p2 + p3);
}

// in-place LN: lane -> (row s = l>>2, quarter q = l&3); stats via shfl_xor.
__device__ inline void wave_ln(float* xs, const float* g, const float* bia, int l) {
    int s = l >> 2, q = l & 3;
    float v[8];
    if (s < SP) {
        const float* row = xs + s * XS_STRIDE + q * 8;
        #pragma unroll
        for (int i = 0; i < 8; ++i) v[i] = row[i];
    } else {
        #pragma unroll
        for (int i = 0; i < 8; ++i) v[i] = 0.f;
    }
    float m = 0.f, m2 = 0.f;
    #pragma unroll
    for (int i = 0; i < 8; ++i) { m += v[i]; m2 += v[i] * v[i]; }
    m += __shfl_xor(m, 1);  m2 += __shfl_xor(m2, 1);
    m += __shfl_xor(m, 2);  m2 += __shfl_xor(m2, 2);
    m *= (1.f / 32.f);
    float var = m2 * (1.f / 32.f) - m * m;
    float r = rsqrtf(var + EPSF);
    if (s < SP) {
        float* row = xs + s * XS_STRIDE + q * 8;
        #pragma unroll
        for (int i = 0; i < 8; ++i)
            row[i] = (v[i] - m) * r * g[q * 8 + i] + bia[q * 8 + i];
    }
}

// absorbed attention: lane -> (qi = l&15, h = l>>4). K/V never materialized.
// score_j = alpha + z . y_j ; o = Wv * (sum_j p_j y_j)/S + bv  (online softmax)
template <int SK>
__device__ inline void wave_attn(const float* xs, const float* xk, int ldk,
                                 const float* Wq, const float* bq,
                                 const float* Wk, const float* bk,   // pre-scaled
                                 const float* Wv, const float* bv,
                                 float* oo, int l) {
    int qi = l & 15, h = l >> 4;
    int qs = (qi < SP) ? qi : SP - 1;           // clamp inactive lanes
    const float* xq = xs + qs * XS_STRIDE;

    float z[32];
    #pragma unroll
    for (int k = 0; k < 32; ++k) z[k] = 0.f;
    float alpha = 0.f;
    #pragma unroll
    for (int d = 0; d < 8; ++d) {
        float qd = bq[h * 8 + d] + dot32(xq, Wq + (h * 8 + d) * 32);
        const float* wr = Wk + (h * 8 + d) * 32;
        alpha += qd * bk[h * 8 + d];
        #pragma unroll
        for (int k = 0; k < 32; ++k) z[k] += qd * wr[k];
    }

    float pc[32];
    #pragma unroll
    for (int k = 0; k < 32; ++k) pc[k] = 0.f;
    float M = -3.0e38f, S = 0.f;
    for (int j = 0; j < SK; ++j) {
        const float* xr = xk + j * ldk;
        float sc_ = alpha + dot32(z, xr);
        float t = fmaxf(M, sc_);
        float a = expf(M - t);        // 0 on first iteration (M=-3e38)
        float p = expf(sc_ - t);
        S = S * a + p;
        #pragma unroll
        for (int k = 0; k < 32; ++k) pc[k] = pc[k] * a + p * xr[k];
        M = t;
    }
    float rinv = 1.f / S;
    #pragma unroll
    for (int k = 0; k < 32; ++k) pc[k] *= rinv;

    if (qi < SP) {
        float* orow = oo + qi * OO_STRIDE + h * 8;
        #pragma unroll
        for (int d = 0; d < 8; ++d)
            orow[d] = bv[h * 8 + d] + dot32(pc, Wv + (h * 8 + d) * 32);
    }
}

// xs[s][e] += bo[e] + oo[s][:] . W[e][:]   lane -> (e = l&31, hi = l>>5)
__device__ inline void wave_outproj(const float* oo, const float* W, const float* bo,
                                    float* xs, int l) {
    int e = l & 31, hi = l >> 5;
    float wrow[32];
    const float* wr = W + e * 32;
    #pragma unroll
    for (int k = 0; k < 32; ++k) wrow[k] = wr[k];
    float be = bo[e];
    #pragma unroll
    for (int j = 0; j < 8; ++j) {
        int s = j * 2 + hi;
        if (s < SP) {
            const float* orow = oo + s * OO_STRIDE;
            xs[s * XS_STRIDE + e] += be + dot32(orow, wrow);
        }
    }
}

__global__ __launch_bounds__(256, 3) void pan_main(
    const int* x_pep, const float* cmhc, const float* emb,
    const float* ln_g, const float* ln_b,
    const float* sa_ow, const float* sa_ob,
    const float* ca_ow, const float* ca_ob,
    const float* fc_w, const float* fc_b,
    const float* proj_w, const float* proj_b,
    const float* fw, const float* fb, const float* pe_tab,
    float* t_out, int nB)
{
    __shared__ float lds[4 * SAMP_LDS];
    const int w = threadIdx.x >> 6;
    const int l = threadIdx.x & 63;
    const int b = blockIdx.x * 4 + w;
    if (b >= nB) return;                     // no block-wide barriers anywhere
    float* xs = lds + w * SAMP_LDS;          // [15 x 36]
    float* sc = xs + 544;                    // scratch: oo [15x36] / FFN half [15x64]

    // embed + PE + tanh
    {
        const int* tok = x_pep + b * SP;
        #pragma unroll
        for (int j = 0; j < 8; ++j) {
            int i = j * 64 + l;
            if (i < SP * 32) {
                int s = i >> 5, e = i & 31;
                xs[s * XS_STRIDE + e] = tanhf(emb[tok[s] * 32 + e] + pe_tab[i]);
            }
        }
    }
    WSYNC();

    const float* cm = cmhc + (size_t)b * SM * 32;

    for (int ly = 0; ly < Lh; ++ly) {
        const float* fwl = fw + ly * 6 * 1024;
        const float* fbl = fb + ly * 6 * 32;

        // LN1 + self-attention + out-proj
        wave_ln(xs, ln_g + (ly * 3 + 0) * 32, ln_b + (ly * 3 + 0) * 32, l);
        WSYNC();
        wave_attn<SP>(xs, xs, XS_STRIDE,
                      fwl + 0 * 1024, fbl + 0 * 32,
                      fwl + 1 * 1024, fbl + 1 * 32,
                      fwl + 2 * 1024, fbl + 2 * 32, sc, l);
        WSYNC();
        wave_outproj(sc, sa_ow + ly * 1024, sa_ob + ly * 32, xs, l);
        WSYNC();

        // LN2 + cross-attention + out-proj
        wave_ln(xs, ln_g + (ly * 3 + 1) * 32, ln_b + (ly * 3 + 1) * 32, l);
        WSYNC();
        wave_attn<SM>(xs, cm, 32,
                      fwl + 3 * 1024, fbl + 3 * 32,
                      fwl + 4 * 1024, fbl + 4 * 32,
                      fwl + 5 * 1024, fbl + 5 * 32, sc, l);
        WSYNC();
        wave_outproj(sc, ca_ow + ly * 1024, ca_ob + ly * 32, xs, l);
        WSYNC();

        // LN3 + FFN (two 64-feature halves through the small scratch)
        wave_ln(xs, ln_g + (ly * 3 + 2) * 32, ln_b + (ly * 3 + 2) * 32, l);
        WSYNC();
        {
            int e = l & 31, hi = l >> 5;
            float acc[8];
            float be = proj_b[ly * 32 + e];
            #pragma unroll
            for (int j = 0; j < 8; ++j) acc[j] = be;

            #pragma unroll
            for (int half = 0; half < 2; ++half) {
                // FFN1: feature f = half*64 + l, all 15 rows
                {
                    int f = half * 64 + l;
                    const float* wr = fc_w + ly * 4096 + f * 32;
                    float wrow[32];
                    #pragma unroll
                    for (int k = 0; k < 32; ++k) wrow[k] = wr[k];
                    float bf = fc_b[ly * 128 + f];
                    for (int s = 0; s < SP; ++s) {
                        float a = bf + dot32(xs + s * XS_STRIDE, wrow);
                        sc[s * 64 + l] =
                            a * 0.5f * (1.f + erff(a * 0.70710678118654752f));
                    }
                }
                WSYNC();
                // FFN2 partial: this half's 64 features in two 32-chunks
                #pragma unroll
                for (int c = 0; c < 2; ++c) {
                    const float* wr = proj_w + ly * 4096 + e * 128 + half * 64 + c * 32;
                    float wrow[32];
                    #pragma unroll
                    for (int k = 0; k < 32; ++k) wrow[k] = wr[k];
                    #pragma unroll
                    for (int j = 0; j < 8; ++j) {
                        int s = j * 2 + hi;
                        if (s < SP)
                            acc[j] += dot32(sc + s * 64 + c * 32, wrow);
                    }
                }
                WSYNC();   // before next half overwrites sc
            }
            #pragma unroll
            for (int j = 0; j < 8; ++j) {
                int s = j * 2 + hi;
                if (s < SP) xs[s * XS_STRIDE + e] += acc[j];
            }
        }
        WSYNC();
    }

    if (l < 32) t_out[(size_t)b * 32 + l] = xs[l];   // x[:,0,:]
}

// ---------------------------------------------------------------------------
// Head kernels (batch-norm chain) — unchanged.
// ---------------------------------------------------------------------------
__global__ __launch_bounds__(256) void head1(const float* t_in, const float* w1,
                                             const float* b1, float* a1,
                                             double* stats, int nB) {
    __shared__ float tb[64 * 32];
    __shared__ float wtf[32 * 129];
    __shared__ float bsh[128];
    __shared__ float rs[128], rss[128];
    int t = threadIdx.x;
    int r0 = blockIdx.x * 64;
    for (int i = t; i < 64 * 32; i += 256) tb[i] = t_in[r0 * 32 + i];
    for (int i = t; i < 128 * 32; i += 256) {
        int f = i >> 5, k = i & 31;
        wtf[k * 129 + f] = w1[i];
    }
    if (t < 128) bsh[t] = b1[t];
    __syncthreads();
    int f = t & 127;
    float ls = 0.f, lss = 0.f;
    for (int rr = t >> 7; rr < 64; rr += 2) {
        float acc = bsh[f];
        #pragma unroll
        for (int k = 0; k < 32; ++k) acc += tb[rr * 32 + k] * wtf[k * 129 + f];
        acc = fmaxf(acc, 0.f);
        a1[(size_t)(r0 + rr) * 128 + f] = acc;
        ls += acc; lss += acc * acc;
    }
    if (t >= 128) { rs[f] = ls; rss[f] = lss; }
    __syncthreads();
    if (t < 128) {
        atomicAdd(&stats[f], (double)(ls + rs[f]));
        atomicAdd(&stats[128 + f], (double)(lss + rss[f]));
    }
}

__global__ __launch_bounds__(256) void head2(const float* t_in, const float* a1,
                                             const float* g, const float* bb,
                                             const float* w2, const float* b2,
                                             float* sbuf, const double* stats,
                                             double* stats2, int nB) {
    __shared__ float scale[128], shift[128];
    __shared__ float wt2[128 * 33];
    __shared__ float rs[256], rss[256];
    int t = threadIdx.x;
    if (t < 128) {
        double m = stats[t] / (double)nB;
        double var = stats[128 + t] / (double)nB - m * m;
        float sc = g[t] * rsqrtf((float)var + EPSF);
        scale[t] = sc;
        shift[t] = bb[t] - (float)m * sc;
    }
    for (int i = t; i < 32 * 128; i += 256) {
        int e = i >> 7, k = i & 127;
        wt2[k * 33 + e] = w2[i];
    }
    __syncthreads();
    int r0 = blockIdx.x * 64;
    int e = t & 31;
    float ls = 0.f, lss = 0.f;
    for (int rr = t >> 5; rr < 64; rr += 8) {
        const float* arow = a1 + (size_t)(r0 + rr) * 128;
        float acc = b2[e];
        #pragma unroll 8
        for (int k = 0; k < 128; ++k)
            acc += (arow[k] * scale[k] + shift[k]) * wt2[k * 33 + e];
        acc = fmaxf(acc, 0.f);
        float sv = t_in[(size_t)(r0 + rr) * 32 + e] + acc;
        sbuf[(size_t)(r0 + rr) * 32 + e] = sv;
        ls += sv; lss += sv * sv;
    }
    rs[t] = ls; rss[t] = lss;
    __syncthreads();
    if (t < 32) {
        float s1 = 0.f, s2 = 0.f;
        for (int j = 0; j < 8; ++j) { s1 += rs[t + 32 * j]; s2 += rss[t + 32 * j]; }
        atomicAdd(&stats2[t], (double)s1);
        atomicAdd(&stats2[32 + t], (double)s2);
    }
}

__global__ __launch_bounds__(256) void head3(const float* sbuf, const float* g,
                                             const float* bb, const float* w,
                                             const float* b, float* rbuf,
                                             const double* stats2, double* stats3,
                                             int nB) {
    __shared__ float scale[32], shift[32];
    __shared__ float wsh[8 * 32];
    __shared__ float rs[256], rss[256];
    int t = threadIdx.x;
    if (t < 32) {
        double m = stats2[t] / (double)nB;
        double var = stats2[32 + t] / (double)nB - m * m;
        float sc = g[t] * rsqrtf((float)var + EPSF);
        scale[t] = sc;
        shift[t] = bb[t] - (float)m * sc;
    }
    if (t < 8 * 32) wsh[t] = w[t];
    __syncthreads();
    int r0 = blockIdx.x * 64;
    int f = t & 7;
    float ls = 0.f, lss = 0.f;
    for (int rr = t >> 3; rr < 64; rr += 32) {
        const float* srow = sbuf + (size_t)(r0 + rr) * 32;
        float acc = b[f];
        #pragma unroll
        for (int k = 0; k < 32; ++k)
            acc += (srow[k] * scale[k] + shift[k]) * wsh[f * 32 + k];
        acc = fmaxf(acc, 0.f);
        rbuf[(size_t)(r0 + rr) * 8 + f] = acc;
        ls += acc; lss += acc * acc;
    }
    rs[t] = ls; rss[t] = lss;
    __syncthreads();
    if (t < 8) {
        float s1 = 0.f, s2 = 0.f;
        for (int j = 0; j < 32; ++j) { s1 += rs[t + 8 * j]; s2 += rss[t + 8 * j]; }
        atomicAdd(&stats3[t], (double)s1);
        atomicAdd(&stats3[8 + t], (double)s2);
    }
}

__global__ __launch_bounds__(256) void head4(const float* rbuf, const float* g,
                                             const float* bb, const float* w2,
                                             const float* b2, float* out,
                                             const double* stats3, int nB) {
    __shared__ float scale[8], shift[8], wv[8];
    int t = threadIdx.x;
    if (t < 8) {
        double m = stats3[t] / (double)nB;
        double var = stats3[8 + t] / (double)nB - m * m;
        float sc = g[t] * rsqrtf((float)var + EPSF);
        scale[t] = sc;
        shift[t] = bb[t] - (float)m * sc;
        wv[t] = w2[t];
    }
    __syncthreads();
    int i = blockIdx.x * 256 + t;
    if (i < nB) {
        const float* rr = rbuf + (size_t)i * 8;
        float acc = b2[0];
        #pragma unroll
        for (int k = 0; k < 8; ++k) acc += (rr[k] * scale[k] + shift[k]) * wv[k];
        out[i] = 1.f / (1.f + expf(-acc));
    }
}

// ---------------------------------------------------------------------------
extern "C" void kernel_launch(void* const* d_in, const int* in_sizes, int n_in,
                              void* d_out, int out_size, void* d_ws, size_t ws_size,
                              hipStream_t stream) {
    const int*   x_pep  = (const int*)  d_in[0];
    const float* cmhc   = (const float*)d_in[1];
    const float* emb    = (const float*)d_in[2];
    const float* ln_g   = (const float*)d_in[3];
    const float* ln_b   = (const float*)d_in[4];
    const float* pre_w  = (const float*)d_in[5];
    const float* pre_b  = (const float*)d_in[6];
    const float* sa_inw = (const float*)d_in[7];
    const float* sa_inb = (const float*)d_in[8];
    const float* sa_ow  = (const float*)d_in[9];
    const float* sa_ob  = (const float*)d_in[10];
    const float* cpre_w = (const float*)d_in[11];
    const float* cpre_b = (const float*)d_in[12];
    const float* ca_inw = (const float*)d_in[13];
    const float* ca_inb = (const float*)d_in[14];
    const float* ca_ow  = (const float*)d_in[15];
    const float* ca_ob  = (const float*)d_in[16];
    const float* fc_w   = (const float*)d_in[17];
    const float* fc_b   = (const float*)d_in[18];
    const float* proj_w = (const float*)d_in[19];
    const float* proj_b = (const float*)d_in[20];
    const float* h1_w1  = (const float*)d_in[21];
    const float* h1_b1  = (const float*)d_in[22];
    const float* h1_g   = (const float*)d_in[23];
    const float* h1_bb  = (const float*)d_in[24];
    const float* h1_w2  = (const float*)d_in[25];
    const float* h1_b2  = (const float*)d_in[26];
    const float* h2_g1  = (const float*)d_in[27];
    const float* h2_bb1 = (const float*)d_in[28];
    const float* h2_w1  = (const float*)d_in[29];
    const float* h2_b1  = (const float*)d_in[30];
    const float* h2_g2  = (const float*)d_in[31];
    const float* h2_bb2 = (const float*)d_in[32];
    const float* h2_w2  = (const float*)d_in[33];
    const float* h2_b2  = (const float*)d_in[34];
    float* out = (float*)d_out;

    const int nB = in_sizes[0] / SP;   // 8192

    float* wsf   = (float*)d_ws;
    float* fw    = wsf;                         // 18*1024
    float* fb    = fw + 18 * 1024;              // 18*32
    float* pe    = fb + 18 * 32;                // 480
    float* t_buf = pe + 480;                    // nB*32
    float* a1    = t_buf + (size_t)nB * 32;     // nB*128
    float* sbuf  = a1 + (size_t)nB * 128;       // nB*32
    float* rbuf  = sbuf + (size_t)nB * 32;      // nB*8
    uintptr_t sp = (uintptr_t)(rbuf + (size_t)nB * 8);
    sp = (sp + 7) & ~(uintptr_t)7;
    double* stats  = (double*)sp;               // 128+128
    double* stats2 = stats + 256;               // 32+32
    double* stats3 = stats2 + 64;               // 8+8

    hipMemsetAsync(stats, 0, 336 * sizeof(double), stream);

    fuse_weights<<<19, 256, 0, stream>>>(pre_w, pre_b, sa_inw, sa_inb,
                                         cpre_w, cpre_b, ca_inw, ca_inb,
                                         fw, fb, pe);

    pan_main<<<(nB + 3) / 4, 256, 0, stream>>>(x_pep, cmhc, emb, ln_g, ln_b,
                                               sa_ow, sa_ob, ca_ow, ca_ob,
                                               fc_w, fc_b, proj_w, proj_b,
                                               fw, fb, pe, t_buf, nB);

    head1<<<nB / 64, 256, 0, stream>>>(t_buf, h1_w1, h1_b1, a1, stats, nB);
    head2<<<nB / 64, 256, 0, stream>>>(t_buf, a1, h1_g, h1_bb, h1_w2, h1_b2,
                                       sbuf, stats, stats2, nB);
    head3<<<nB / 64, 256, 0, stream>>>(sbuf, h2_g1, h2_bb1, h2_w1, h2_b1,
                                       rbuf, stats2, stats3, nB);
    head4<<<(nB + 255) / 256, 256, 0, stream>>>(rbuf, h2_g2, h2_bb2, h2_w2, h2_b2,
                                                out, stats3, nB);
}

// Round 13
// 1937.561 us; speedup vs baseline: 2.7651x; 2.7651x over previous
//
#include <hip/hip_runtime.h>
#include <math.h>

#define Hh    4
#define Lh    3
#define SP    15
#define SM    74
#define EPSF  1e-5f

// wave-synchronous fence (one wave per block -> no __syncthreads needed)
#define WSYNC() do { __builtin_amdgcn_wave_barrier(); asm volatile("" ::: "memory"); } while (0)

typedef float4 f4;
// 32 floats in 8 named float4s -- named members defeat scratch demotion (SROA-safe)
struct W8 { f4 a,b,c,d,e,f,g,h; };

__device__ inline W8 ld_row32(const float* p) {
    const f4* q = (const f4*)p;
    W8 w;
    w.a = q[0]; w.b = q[1]; w.c = q[2]; w.d = q[3];
    w.e = q[4]; w.f = q[5]; w.g = q[6]; w.h = q[7];
    return w;
}
__device__ inline float dot4(f4 x, f4 y) {
    return x.x*y.x + x.y*y.y + x.z*y.z + x.w*y.w;
}
__device__ inline float dotW8(const W8& w, const W8& r) {
    return ((dot4(w.a,r.a) + dot4(w.b,r.b)) + (dot4(w.c,r.c) + dot4(w.d,r.d)))
         + ((dot4(w.e,r.e) + dot4(w.f,r.f)) + (dot4(w.g,r.g) + dot4(w.h,r.h)));
}

// ---------------------------------------------------------------------------
// Setup: fuse pre_qkv into attention in-projections; K-mats pre-scaled by
// 1/sqrt(8); block 18 builds the positional-encoding table.
// ---------------------------------------------------------------------------
__global__ void fuse_weights(const float* pre_w, const float* pre_b,
                             const float* sa_inw, const float* sa_inb,
                             const float* cpre_w, const float* cpre_b,
                             const float* ca_inw, const float* ca_inb,
                             float* fw, float* fb, float* pe) {
    int id = blockIdx.x;            // 0..17 weights, 18 = PE table
    if (id == 18) {
        for (int i = threadIdx.x; i < SP * 32; i += blockDim.x) {
            int s = i >> 5, e = i & 31;
            float div = expf(-(float)(e & ~1) * 0.28782313662425572f); // ln(1e4)/32
            float ang = (float)s * div;
            pe[i] = (e & 1) ? cosf(ang) : sinf(ang);
        }
        return;
    }
    int l = id / 6, which = id % 6;
    int j = which % 3;
    bool cross = which >= 3;
    float scale = (j == 1) ? 0.35355339059327373f : 1.f;   // fold 1/sqrt(Dh) into K
    const float* A  = (cross ? ca_inw : sa_inw) + l * 96 * 32 + j * 32 * 32;
    const float* ab = (cross ? ca_inb : sa_inb) + l * 96 + j * 32;
    const float* P  = (cross ? cpre_w : pre_w) + (l * 3 + j) * 1024;
    const float* pb = (cross ? cpre_b : pre_b) + (l * 3 + j) * 32;
    float* W = fw + id * 1024;
    float* b = fb + id * 32;
    for (int i = threadIdx.x; i < 1024; i += blockDim.x) {
        int e = i >> 5, k = i & 31;
        float acc = 0.f;
        #pragma unroll
        for (int m = 0; m < 32; ++m) acc += A[e * 32 + m] * P[m * 32 + k];
        W[i] = acc * scale;
    }
    for (int e = threadIdx.x; e < 32; e += blockDim.x) {
        float acc = ab[e];
        #pragma unroll
        for (int m = 0; m < 32; ++m) acc += A[e * 32 + m] * pb[m];
        b[e] = acc * scale;
    }
}

// ---------------------------------------------------------------------------
// in-place LN; lane -> (row s = l>>2, quarter q = l&3); stats via shfl_xor.
// ---------------------------------------------------------------------------
__device__ inline void wave_ln(float* xs, const float* g, const float* bia, int l) {
    int s = l >> 2, q = l & 3;
    int ss = (s < SP) ? s : SP - 1;
    f4* row = (f4*)(xs + ss * 36 + q * 8);
    f4 a = row[0], b = row[1];
    float m  = (a.x + a.y) + (a.z + a.w) + (b.x + b.y) + (b.z + b.w);
    float m2 = (a.x*a.x + a.y*a.y) + (a.z*a.z + a.w*a.w)
             + (b.x*b.x + b.y*b.y) + (b.z*b.z + b.w*b.w);
    m  += __shfl_xor(m, 1);  m2 += __shfl_xor(m2, 1);
    m  += __shfl_xor(m, 2);  m2 += __shfl_xor(m2, 2);
    m *= (1.f / 32.f);
    float var = m2 * (1.f / 32.f) - m * m;
    float r = rsqrtf(var + EPSF);
    const f4* gg = (const f4*)(g + q * 8);
    const f4* bb = (const f4*)(bia + q * 8);
    f4 g0 = gg[0], g1 = gg[1], b0 = bb[0], b1 = bb[1];
    if (s < SP) {
        f4 o0, o1;
        o0.x = (a.x - m) * r * g0.x + b0.x;  o0.y = (a.y - m) * r * g0.y + b0.y;
        o0.z = (a.z - m) * r * g0.z + b0.z;  o0.w = (a.w - m) * r * g0.w + b0.w;
        o1.x = (b.x - m) * r * g1.x + b1.x;  o1.y = (b.y - m) * r * g1.y + b1.y;
        o1.z = (b.z - m) * r * g1.z + b1.z;  o1.w = (b.w - m) * r * g1.w + b1.w;
        row[0] = o0; row[1] = o1;
    }
}

// flash attention over materialized K/V in LDS; per-lane state = q8,o8,M,S only
struct O8 { f4 lo, hi; };
template <int SK>
__device__ inline O8 attn_kv(f4 qlo, f4 qhi, const float* kb, const float* vb, int hb) {
    f4 olo = {0.f,0.f,0.f,0.f}, ohi = {0.f,0.f,0.f,0.f};
    float M = -3.0e38f, S = 0.f;
    for (int j = 0; j < SK; ++j) {
        const f4* kr = (const f4*)(kb + j * 32 + hb);
        float sc = dot4(qlo, kr[0]) + dot4(qhi, kr[1]);
        float t = fmaxf(M, sc);
        float a = __expf(M - t);      // 0 on first iteration
        float p = __expf(sc - t);
        S = S * a + p;
        const f4* vr = (const f4*)(vb + j * 32 + hb);
        f4 v0 = vr[0], v1 = vr[1];
        olo.x = olo.x*a + p*v0.x;  olo.y = olo.y*a + p*v0.y;
        olo.z = olo.z*a + p*v0.z;  olo.w = olo.w*a + p*v0.w;
        ohi.x = ohi.x*a + p*v1.x;  ohi.y = ohi.y*a + p*v1.y;
        ohi.z = ohi.z*a + p*v1.z;  ohi.w = ohi.w*a + p*v1.w;
        M = t;
    }
    float rv = 1.f / S;
    O8 o;
    o.lo.x = olo.x*rv; o.lo.y = olo.y*rv; o.lo.z = olo.z*rv; o.lo.w = olo.w*rv;
    o.hi.x = ohi.x*rv; o.hi.y = ohi.y*rv; o.hi.z = ohi.z*rv; o.hi.w = ohi.w*rv;
    return o;
}

// compute q8 for lane (qi,h) from LDS row xq with fused Wq/bq
__device__ inline void make_q8(const float* xqp, const float* Wq, const float* bq,
                               int hb, f4& qlo, f4& qhi) {
    W8 xq = ld_row32(xqp);
    qlo.x = bq[hb+0] + dotW8(ld_row32(Wq + (hb+0)*32), xq);
    qlo.y = bq[hb+1] + dotW8(ld_row32(Wq + (hb+1)*32), xq);
    qlo.z = bq[hb+2] + dotW8(ld_row32(Wq + (hb+2)*32), xq);
    qlo.w = bq[hb+3] + dotW8(ld_row32(Wq + (hb+3)*32), xq);
    qhi.x = bq[hb+4] + dotW8(ld_row32(Wq + (hb+4)*32), xq);
    qhi.y = bq[hb+5] + dotW8(ld_row32(Wq + (hb+5)*32), xq);
    qhi.z = bq[hb+6] + dotW8(ld_row32(Wq + (hb+6)*32), xq);
    qhi.w = bq[hb+7] + dotW8(ld_row32(Wq + (hb+7)*32), xq);
}

// ---------------------------------------------------------------------------
// One wave (64-thread block) per sample. K/V materialized in LDS.
// ---------------------------------------------------------------------------
__global__ __launch_bounds__(64) void pan_main(
    const int* x_pep, const float* cmhc, const float* emb,
    const float* ln_g, const float* ln_b,
    const float* sa_ow, const float* sa_ob,
    const float* ca_ow, const float* ca_ob,
    const float* fc_w, const float* fc_b,
    const float* proj_w, const float* proj_b,
    const float* fw, const float* fb, const float* pe_tab,
    float* t_out, int nB)
{
    __shared__ __align__(16) float xs[SP * 36 + 4];     // 544
    __shared__ __align__(16) float kbuf[SM * 32];       // 2368; also FFN hidden [15][128]
    __shared__ __align__(16) float vbuf[SM * 32];       // 2368
    __shared__ __align__(16) float oo[SP * 36];         // 540

    const int l  = threadIdx.x;
    const int b  = blockIdx.x;
    const int qi = l & 15, hb = (l >> 4) * 8;
    const int e32 = l & 31, hi = l >> 5;

    // embed + PE + tanh
    {
        const int* tok = x_pep + b * SP;
        for (int i = l; i < SP * 32; i += 64) {
            int s = i >> 5, e = i & 31;
            xs[s * 36 + e] = tanhf(emb[tok[s] * 32 + e] + pe_tab[i]);
        }
    }
    WSYNC();
    const float* cm = cmhc + (size_t)b * SM * 32;

    for (int ly = 0; ly < Lh; ++ly) {
        const float* fwl = fw + ly * 6 * 1024;
        const float* fbl = fb + ly * 6 * 32;

        // ---- LN1 (in place) ----
        wave_ln(xs, ln_g + (ly*3+0)*32, ln_b + (ly*3+0)*32, l);
        WSYNC();

        // self K/V -> LDS: half-wave 0 does K, half-wave 1 does V
        {
            const float* Wm = fwl + (hi ? 2*1024 : 1*1024);
            const float* bm = fbl + (hi ? 64 : 32);
            float* dst = hi ? vbuf : kbuf;
            W8 w = ld_row32(Wm + e32 * 32);
            float bias = bm[e32];
            for (int s = 0; s < SP; ++s) {
                W8 r = ld_row32(xs + s * 36);
                dst[s * 32 + e32] = bias + dotW8(w, r);
            }
        }
        // q8 (reads xs only -- independent of K/V writes)
        f4 qlo, qhi;
        {
            int qs = (qi < SP) ? qi : SP - 1;
            make_q8(xs + qs * 36, fwl, fbl, hb, qlo, qhi);
        }
        WSYNC();
        // self attention
        {
            O8 o = attn_kv<SP>(qlo, qhi, kbuf, vbuf, hb);
            if (qi < SP) {
                f4* od = (f4*)(oo + qi * 36 + hb);
                od[0] = o.lo; od[1] = o.hi;
            }
        }
        WSYNC();
        // self out-proj (+residual into xs)
        {
            W8 w = ld_row32(sa_ow + ly * 1024 + e32 * 32);
            float be = sa_ob[ly * 32 + e32];
            for (int jj = 0; jj < 8; ++jj) {
                int s = jj * 2 + hi;
                if (s < SP) {
                    W8 r = ld_row32(oo + s * 36);
                    xs[s * 36 + e32] += be + dotW8(w, r);
                }
            }
        }
        WSYNC();

        // ---- LN2 ----
        wave_ln(xs, ln_g + (ly*3+1)*32, ln_b + (ly*3+1)*32, l);
        WSYNC();
        // cross K/V from cmhc (global, L2-broadcast)
        {
            const float* Wm = fwl + (hi ? 5*1024 : 4*1024);
            const float* bm = fbl + (hi ? 160 : 128);
            float* dst = hi ? vbuf : kbuf;
            W8 w = ld_row32(Wm + e32 * 32);
            float bias = bm[e32];
            #pragma unroll 2
            for (int j = 0; j < SM; ++j) {
                W8 r = ld_row32(cm + j * 32);
                dst[j * 32 + e32] = bias + dotW8(w, r);
            }
        }
        {
            int qs = (qi < SP) ? qi : SP - 1;
            make_q8(xs + qs * 36, fwl + 3*1024, fbl + 96, hb, qlo, qhi);
        }
        WSYNC();
        // cross attention
        {
            O8 o = attn_kv<SM>(qlo, qhi, kbuf, vbuf, hb);
            if (qi < SP) {
                f4* od = (f4*)(oo + qi * 36 + hb);
                od[0] = o.lo; od[1] = o.hi;
            }
        }
        WSYNC();
        // cross out-proj
        {
            W8 w = ld_row32(ca_ow + ly * 1024 + e32 * 32);
            float be = ca_ob[ly * 32 + e32];
            for (int jj = 0; jj < 8; ++jj) {
                int s = jj * 2 + hi;
                if (s < SP) {
                    W8 r = ld_row32(oo + s * 36);
                    xs[s * 36 + e32] += be + dotW8(w, r);
                }
            }
        }
        WSYNC();

        // ---- LN3 + FFN ----
        wave_ln(xs, ln_g + (ly*3+2)*32, ln_b + (ly*3+2)*32, l);
        WSYNC();
        // FFN1: hidden [15][128] into kbuf; each lane owns features l and l+64
        #pragma unroll
        for (int half = 0; half < 2; ++half) {
            int ff = half * 64 + l;
            W8 w = ld_row32(fc_w + ly * 4096 + ff * 32);
            float bf = fc_b[ly * 128 + ff];
            for (int s = 0; s < SP; ++s) {
                W8 r = ld_row32(xs + s * 36);
                float a = bf + dotW8(w, r);
                kbuf[s * 128 + ff] = a * 0.5f * (1.f + erff(a * 0.70710678118654752f));
            }
        }
        WSYNC();
        // FFN2 (+residual)
        {
            const float* W = proj_w + ly * 4096 + e32 * 128;
            float be = proj_b[ly * 32 + e32];
            for (int jj = 0; jj < 8; ++jj) {
                int s = jj * 2 + hi;
                if (s < SP) {
                    const float* hr = kbuf + s * 128;
                    float acc = be;
                    acc += dotW8(ld_row32(W),      ld_row32(hr));
                    acc += dotW8(ld_row32(W + 32), ld_row32(hr + 32));
                    acc += dotW8(ld_row32(W + 64), ld_row32(hr + 64));
                    acc += dotW8(ld_row32(W + 96), ld_row32(hr + 96));
                    xs[s * 36 + e32] += acc;
                }
            }
        }
        WSYNC();
    }

    if (l < 32) t_out[(size_t)b * 32 + l] = xs[l];   // x[:,0,:]
}

// ---------------------------------------------------------------------------
// Head kernels (batch-norm chain) — unchanged.
// ---------------------------------------------------------------------------
__global__ __launch_bounds__(256) void head1(const float* t_in, const float* w1,
                                             const float* b1, float* a1,
                                             double* stats, int nB) {
    __shared__ float tb[64 * 32];
    __shared__ float wtf[32 * 129];
    __shared__ float bsh[128];
    __shared__ float rs[128], rss[128];
    int t = threadIdx.x;
    int r0 = blockIdx.x * 64;
    for (int i = t; i < 64 * 32; i += 256) tb[i] = t_in[r0 * 32 + i];
    for (int i = t; i < 128 * 32; i += 256) {
        int f = i >> 5, k = i & 31;
        wtf[k * 129 + f] = w1[i];
    }
    if (t < 128) bsh[t] = b1[t];
    __syncthreads();
    int f = t & 127;
    float ls = 0.f, lss = 0.f;
    for (int rr = t >> 7; rr < 64; rr += 2) {
        float acc = bsh[f];
        #pragma unroll
        for (int k = 0; k < 32; ++k) acc += tb[rr * 32 + k] * wtf[k * 129 + f];
        acc = fmaxf(acc, 0.f);
        a1[(size_t)(r0 + rr) * 128 + f] = acc;
        ls += acc; lss += acc * acc;
    }
    if (t >= 128) { rs[f] = ls; rss[f] = lss; }
    __syncthreads();
    if (t < 128) {
        atomicAdd(&stats[f], (double)(ls + rs[f]));
        atomicAdd(&stats[128 + f], (double)(lss + rss[f]));
    }
}

__global__ __launch_bounds__(256) void head2(const float* t_in, const float* a1,
                                             const float* g, const float* bb,
                                             const float* w2, const float* b2,
                                             float* sbuf, const double* stats,
                                             double* stats2, int nB) {
    __shared__ float scale[128], shift[128];
    __shared__ float wt2[128 * 33];
    __shared__ float rs[256], rss[256];
    int t = threadIdx.x;
    if (t < 128) {
        double m = stats[t] / (double)nB;
        double var = stats[128 + t] / (double)nB - m * m;
        float sc = g[t] * rsqrtf((float)var + EPSF);
        scale[t] = sc;
        shift[t] = bb[t] - (float)m * sc;
    }
    for (int i = t; i < 32 * 128; i += 256) {
        int e = i >> 7, k = i & 127;
        wt2[k * 33 + e] = w2[i];
    }
    __syncthreads();
    int r0 = blockIdx.x * 64;
    int e = t & 31;
    float ls = 0.f, lss = 0.f;
    for (int rr = t >> 5; rr < 64; rr += 8) {
        const float* arow = a1 + (size_t)(r0 + rr) * 128;
        float acc = b2[e];
        #pragma unroll 8
        for (int k = 0; k < 128; ++k)
            acc += (arow[k] * scale[k] + shift[k]) * wt2[k * 33 + e];
        acc = fmaxf(acc, 0.f);
        float sv = t_in[(size_t)(r0 + rr) * 32 + e] + acc;
        sbuf[(size_t)(r0 + rr) * 32 + e] = sv;
        ls += sv; lss += sv * sv;
    }
    rs[t] = ls; rss[t] = lss;
    __syncthreads();
    if (t < 32) {
        float s1 = 0.f, s2 = 0.f;
        for (int j = 0; j < 8; ++j) { s1 += rs[t + 32 * j]; s2 += rss[t + 32 * j]; }
        atomicAdd(&stats2[t], (double)s1);
        atomicAdd(&stats2[32 + t], (double)s2);
    }
}

__global__ __launch_bounds__(256) void head3(const float* sbuf, const float* g,
                                             const float* bb, const float* w,
                                             const float* b, float* rbuf,
                                             const double* stats2, double* stats3,
                                             int nB) {
    __shared__ float scale[32], shift[32];
    __shared__ float wsh[8 * 32];
    __shared__ float rs[256], rss[256];
    int t = threadIdx.x;
    if (t < 32) {
        double m = stats2[t] / (double)nB;
        double var = stats2[32 + t] / (double)nB - m * m;
        float sc = g[t] * rsqrtf((float)var + EPSF);
        scale[t] = sc;
        shift[t] = bb[t] - (float)m * sc;
    }
    if (t < 8 * 32) wsh[t] = w[t];
    __syncthreads();
    int r0 = blockIdx.x * 64;
    int f = t & 7;
    float ls = 0.f, lss = 0.f;
    for (int rr = t >> 3; rr < 64; rr += 32) {
        const float* srow = sbuf + (size_t)(r0 + rr) * 32;
        float acc = b[f];
        #pragma unroll
        for (int k = 0; k < 32; ++k)
            acc += (srow[k] * scale[k] + shift[k]) * wsh[f * 32 + k];
        acc = fmaxf(acc, 0.f);
        rbuf[(size_t)(r0 + rr) * 8 + f] = acc;
        ls += acc; lss += acc * acc;
    }
    rs[t] = ls; rss[t] = lss;
    __syncthreads();
    if (t < 8) {
        float s1 = 0.f, s2 = 0.f;
        for (int j = 0; j < 32; ++j) { s1 += rs[t + 8 * j]; s2 += rss[t + 8 * j]; }
        atomicAdd(&stats3[t], (double)s1);
        atomicAdd(&stats3[8 + t], (double)s2);
    }
}

__global__ __launch_bounds__(256) void head4(const float* rbuf, const float* g,
                                             const float* bb, const float* w2,
                                             const float* b2, float* out,
                                             const double* stats3, int nB) {
    __shared__ float scale[8], shift[8], wv[8];
    int t = threadIdx.x;
    if (t < 8) {
        double m = stats3[t] / (double)nB;
        double var = stats3[8 + t] / (double)nB - m * m;
        float sc = g[t] * rsqrtf((float)var + EPSF);
        scale[t] = sc;
        shift[t] = bb[t] - (float)m * sc;
        wv[t] = w2[t];
    }
    __syncthreads();
    int i = blockIdx.x * 256 + t;
    if (i < nB) {
        const float* rr = rbuf + (size_t)i * 8;
        float acc = b2[0];
        #pragma unroll
        for (int k = 0; k < 8; ++k) acc += (rr[k] * scale[k] + shift[k]) * wv[k];
        out[i] = 1.f / (1.f + expf(-acc));
    }
}

// ---------------------------------------------------------------------------
extern "C" void kernel_launch(void* const* d_in, const int* in_sizes, int n_in,
                              void* d_out, int out_size, void* d_ws, size_t ws_size,
                              hipStream_t stream) {
    const int*   x_pep  = (const int*)  d_in[0];
    const float* cmhc   = (const float*)d_in[1];
    const float* emb    = (const float*)d_in[2];
    const float* ln_g   = (const float*)d_in[3];
    const float* ln_b   = (const float*)d_in[4];
    const float* pre_w  = (const float*)d_in[5];
    const float* pre_b  = (const float*)d_in[6];
    const float* sa_inw = (const float*)d_in[7];
    const float* sa_inb = (const float*)d_in[8];
    const float* sa_ow  = (const float*)d_in[9];
    const float* sa_ob  = (const float*)d_in[10];
    const float* cpre_w = (const float*)d_in[11];
    const float* cpre_b = (const float*)d_in[12];
    const float* ca_inw = (const float*)d_in[13];
    const float* ca_inb = (const float*)d_in[14];
    const float* ca_ow  = (const float*)d_in[15];
    const float* ca_ob  = (const float*)d_in[16];
    const float* fc_w   = (const float*)d_in[17];
    const float* fc_b   = (const float*)d_in[18];
    const float* proj_w = (const float*)d_in[19];
    const float* proj_b = (const float*)d_in[20];
    const float* h1_w1  = (const float*)d_in[21];
    const float* h1_b1  = (const float*)d_in[22];
    const float* h1_g   = (const float*)d_in[23];
    const float* h1_bb  = (const float*)d_in[24];
    const float* h1_w2  = (const float*)d_in[25];
    const float* h1_b2  = (const float*)d_in[26];
    const float* h2_g1  = (const float*)d_in[27];
    const float* h2_bb1 = (const float*)d_in[28];
    const float* h2_w1  = (const float*)d_in[29];
    const float* h2_b1  = (const float*)d_in[30];
    const float* h2_g2  = (const float*)d_in[31];
    const float* h2_bb2 = (const float*)d_in[32];
    const float* h2_w2  = (const float*)d_in[33];
    const float* h2_b2  = (const float*)d_in[34];
    float* out = (float*)d_out;

    const int nB = in_sizes[0] / SP;   // 8192

    float* wsf   = (float*)d_ws;
    float* fw    = wsf;                         // 18*1024
    float* fb    = fw + 18 * 1024;              // 18*32
    float* pe    = fb + 18 * 32;                // 480
    float* t_buf = pe + 480;                    // nB*32
    float* a1    = t_buf + (size_t)nB * 32;     // nB*128
    float* sbuf  = a1 + (size_t)nB * 128;       // nB*32
    float* rbuf  = sbuf + (size_t)nB * 32;      // nB*8
    uintptr_t sp = (uintptr_t)(rbuf + (size_t)nB * 8);
    sp = (sp + 7) & ~(uintptr_t)7;
    double* stats  = (double*)sp;               // 128+128
    double* stats2 = stats + 256;               // 32+32
    double* stats3 = stats2 + 64;               // 8+8

    hipMemsetAsync(stats, 0, 336 * sizeof(double), stream);

    fuse_weights<<<19, 256, 0, stream>>>(pre_w, pre_b, sa_inw, sa_inb,
                                         cpre_w, cpre_b, ca_inw, ca_inb,
                                         fw, fb, pe);

    pan_main<<<nB, 64, 0, stream>>>(x_pep, cmhc, emb, ln_g, ln_b,
                                    sa_ow, sa_ob, ca_ow, ca_ob,
                                    fc_w, fc_b, proj_w, proj_b,
                                    fw, fb, pe, t_buf, nB);

    head1<<<nB / 64, 256, 0, stream>>>(t_buf, h1_w1, h1_b1, a1, stats, nB);
    head2<<<nB / 64, 256, 0, stream>>>(t_buf, a1, h1_g, h1_bb, h1_w2, h1_b2,
                                       sbuf, stats, stats2, nB);
    head3<<<nB / 64, 256, 0, stream>>>(sbuf, h2_g1, h2_bb1, h2_w1, h2_b1,
                                       rbuf, stats2, stats3, nB);
    head4<<<(nB + 255) / 256, 256, 0, stream>>>(rbuf, h2_g2, h2_bb2, h2_w2, h2_b2,
                                                out, stats3, nB);
}